// Round 1
// baseline (2278.383 us; speedup 1.0000x reference)
//
#include <hip/hip_runtime.h>
#include <hip/hip_bf16.h>
#include <cstdint>

// Problem constants (B=2,S=1024,D=1024; L=2,E=8,F=2048; k=2)
#define T_TOKENS 2048
#define DDIM 1024
#define FDIM 2048
#define NEXP 8
#define NLAYER 2
#define BM 128
#define RMAX 5120  // 2048*2 + 8*(BM-1) = 5112, rounded up

// ---------------- routing: scores = |x . proto_e|, top-2, softmax ----------------
__global__ __launch_bounds__(256) void route_kernel(
    const float* __restrict__ x, const float* __restrict__ protos,
    int* __restrict__ eid, float* __restrict__ wgt) {
  const int t = blockIdx.x;
  const int tid = threadIdx.x;
  const float* xr = x + (size_t)t * DDIM;
  __shared__ float red[NEXP][256];
  float acc[NEXP];
#pragma unroll
  for (int e = 0; e < NEXP; ++e) acc[e] = 0.f;
  for (int d = tid; d < DDIM; d += 256) {
    float xv = xr[d];
#pragma unroll
    for (int e = 0; e < NEXP; ++e) acc[e] += xv * protos[e * DDIM + d];
  }
#pragma unroll
  for (int e = 0; e < NEXP; ++e) red[e][tid] = acc[e];
  __syncthreads();
  for (int s = 128; s > 0; s >>= 1) {
    if (tid < s) {
#pragma unroll
      for (int e = 0; e < NEXP; ++e) red[e][tid] += red[e][tid + s];
    }
    __syncthreads();
  }
  if (tid == 0) {
    float m1 = -1.f, m2 = -1.f;
    int i1 = 0, i2 = 0;
#pragma unroll
    for (int e = 0; e < NEXP; ++e) {
      float s = fabsf(red[e][0]);
      if (s > m1) { m2 = m1; i2 = i1; m1 = s; i1 = e; }
      else if (s > m2) { m2 = s; i2 = e; }
    }
    float e2 = __expf(m2 - m1);
    float z = 1.f + e2;
    eid[t * 2] = i1;
    eid[t * 2 + 1] = i2;
    wgt[t * 2] = 1.f / z;
    wgt[t * 2 + 1] = e2 / z;
  }
}

// ------------- compaction: ordered per-expert token lists, padded to BM -------------
__global__ void compact_kernel(const int* __restrict__ eid, int* __restrict__ cnt,
                               int* __restrict__ offp, int* __restrict__ row2token,
                               int* __restrict__ pos) {
  const int e = threadIdx.x;
  __shared__ int s_cnt[NEXP], s_off[NEXP];
  if (e < NEXP) {
    int c = 0;
    for (int t = 0; t < T_TOKENS * 2; ++t)
      if (eid[t] == e) c++;
    s_cnt[e] = c;
  }
  __syncthreads();
  if (e == 0) {
    int o = 0;
    for (int i = 0; i < NEXP; ++i) {
      s_off[i] = o;
      o += (s_cnt[i] + BM - 1) & ~(BM - 1);
    }
    for (int r = o; r < RMAX; ++r) row2token[r] = -1;  // tail: dummy rows
  }
  __syncthreads();
  if (e < NEXP) {
    int cur = s_off[e];
    for (int t = 0; t < T_TOKENS * 2; ++t) {
      if (eid[t] == e) {
        row2token[cur] = t >> 1;  // token index
        pos[t] = cur;             // row for (token, slot)
        cur++;
      }
    }
    const int end = s_off[e] + ((s_cnt[e] + BM - 1) & ~(BM - 1));
    for (; cur < end; ++cur) row2token[cur] = -1;  // in-region padding rows
    cnt[e] = s_cnt[e];
    offp[e] = s_off[e];
  }
}

// ------------- gather x rows (f32) into contiguous padded row buffer -------------
__global__ __launch_bounds__(256) void gather_kernel(
    const float* __restrict__ x, const int* __restrict__ row2token,
    float* __restrict__ Ag) {
  const int r = blockIdx.x;
  const int t = row2token[r];
  float4 v = make_float4(0.f, 0.f, 0.f, 0.f);
  if (t >= 0) v = *(const float4*)(x + (size_t)t * DDIM + threadIdx.x * 4);
  *(float4*)(Ag + (size_t)r * DDIM + threadIdx.x * 4) = v;
}

// ------------- grouped expert GEMM: C[r][n] = (relu)(sum_k A[r][k]*B_e[k][n]) -------------
// A: [RMAX][K] row-major (rows are padded per-expert regions), B_e = Bbase + e*K*N
// 128x128 tile, BK=16, 256 threads, 8x8 per thread, all f32.
template <bool RELU>
__global__ __launch_bounds__(256) void gemm_expert(
    const float* __restrict__ A, const float* __restrict__ Bbase,
    float* __restrict__ C, const int* __restrict__ cnt,
    const int* __restrict__ offp, int K, int N) {
  const int e = blockIdx.z;
  const int cp = (cnt[e] + BM - 1) & ~(BM - 1);
  if ((int)(blockIdx.y * BM) >= cp) return;
  const int row0 = offp[e] + blockIdx.y * BM;
  const int n0 = blockIdx.x * 128;
  const float* Bp = Bbase + (size_t)e * K * N;

  __shared__ float As[16][132];  // [k][m], stride 132 (16B-aligned rows, 2-way banks)
  __shared__ float Bs[16][132];  // [k][n]

  const int tid = threadIdx.x;
  const int tx = tid & 15, ty = tid >> 4;

  float acc[8][8];
#pragma unroll
  for (int i = 0; i < 8; ++i)
#pragma unroll
    for (int j = 0; j < 8; ++j) acc[i][j] = 0.f;

  const int ka = tid & 15;    // A: k offset (fixed per thread)
  const int ma0 = tid >> 4;   // A: row, +16 per iter
  const int nb = tid & 127;   // B: col (fixed per thread)
  const int kb0 = tid >> 7;   // B: k, +2 per iter

  for (int k0 = 0; k0 < K; k0 += 16) {
#pragma unroll
    for (int i = 0; i < 8; ++i) {
      const int m = ma0 + i * 16;
      As[ka][m] = A[(size_t)(row0 + m) * K + k0 + ka];
    }
#pragma unroll
    for (int i = 0; i < 8; ++i) {
      const int kk = kb0 + i * 2;
      Bs[kk][nb] = Bp[(size_t)(k0 + kk) * N + n0 + nb];
    }
    __syncthreads();
#pragma unroll
    for (int kk = 0; kk < 16; ++kk) {
      float a[8], b[8];
      *(float4*)&a[0] = *(const float4*)&As[kk][ty * 8];
      *(float4*)&a[4] = *(const float4*)&As[kk][ty * 8 + 4];
      *(float4*)&b[0] = *(const float4*)&Bs[kk][tx * 8];
      *(float4*)&b[4] = *(const float4*)&Bs[kk][tx * 8 + 4];
#pragma unroll
      for (int i = 0; i < 8; ++i)
#pragma unroll
        for (int j = 0; j < 8; ++j) acc[i][j] += a[i] * b[j];
    }
    __syncthreads();
  }

#pragma unroll
  for (int i = 0; i < 8; ++i) {
    const int row = row0 + ty * 8 + i;
    float* Cr = C + (size_t)row * N + n0 + tx * 8;
#pragma unroll
    for (int j = 0; j < 8; ++j) {
      float v = acc[i][j];
      if (RELU) v = fmaxf(v, 0.f);
      Cr[j] = v;
    }
  }
}

// ------------- apply: x[t] += w0*y[pos0] + w1*y[pos1] -------------
__global__ __launch_bounds__(256) void apply_kernel(
    const float* __restrict__ ytmp, const int* __restrict__ pos,
    const float* __restrict__ wgt, float* __restrict__ x) {
  const int t = blockIdx.x;
  const int c = threadIdx.x * 4;
  const int p0 = pos[t * 2], p1 = pos[t * 2 + 1];
  const float w0 = wgt[t * 2], w1 = wgt[t * 2 + 1];
  float4 xa = *(float4*)(x + (size_t)t * DDIM + c);
  const float4 y0 = *(const float4*)(ytmp + (size_t)p0 * DDIM + c);
  const float4 y1 = *(const float4*)(ytmp + (size_t)p1 * DDIM + c);
  xa.x += w0 * y0.x + w1 * y1.x;
  xa.y += w0 * y0.y + w1 * y1.y;
  xa.z += w0 * y0.z + w1 * y1.z;
  xa.w += w0 * y0.w + w1 * y1.w;
  *(float4*)(x + (size_t)t * DDIM + c) = xa;
}

extern "C" void kernel_launch(void* const* d_in, const int* in_sizes, int n_in,
                              void* d_out, int out_size, void* d_ws, size_t ws_size,
                              hipStream_t stream) {
  const float* x = (const float*)d_in[0];
  const float* protos = (const float*)d_in[1];
  const float* W1 = (const float*)d_in[2];
  const float* W2 = (const float*)d_in[3];
  float* xcur = (float*)d_out;  // working residual stream buffer

  // workspace layout (f32): Ag [RMAX][D], h [RMAX][F], ytmp [RMAX][D], then meta
  float* Ag = (float*)d_ws;
  float* h = Ag + (size_t)RMAX * DDIM;
  float* ytmp = h + (size_t)RMAX * FDIM;
  float* wgt = ytmp + (size_t)RMAX * DDIM;
  int* eid = (int*)(wgt + T_TOKENS * 2);
  int* pos = eid + T_TOKENS * 2;
  int* cnt = pos + T_TOKENS * 2;
  int* offp = cnt + NEXP;
  int* row2token = offp + NEXP;

  hipMemcpyAsync(xcur, x, (size_t)T_TOKENS * DDIM * sizeof(float),
                 hipMemcpyDeviceToDevice, stream);

  for (int l = 0; l < NLAYER; ++l) {
    route_kernel<<<T_TOKENS, 256, 0, stream>>>(
        xcur, protos + (size_t)l * NEXP * DDIM, eid, wgt);
    compact_kernel<<<1, 64, 0, stream>>>(eid, cnt, offp, row2token, pos);
    gather_kernel<<<RMAX, 256, 0, stream>>>(xcur, row2token, Ag);
    gemm_expert<true><<<dim3(FDIM / 128, 16, NEXP), 256, 0, stream>>>(
        Ag, W1 + (size_t)l * NEXP * DDIM * FDIM, h, cnt, offp, DDIM, FDIM);
    gemm_expert<false><<<dim3(DDIM / 128, 16, NEXP), 256, 0, stream>>>(
        h, W2 + (size_t)l * NEXP * FDIM * DDIM, ytmp, cnt, offp, FDIM, DDIM);
    apply_kernel<<<T_TOKENS, 256, 0, stream>>>(ytmp, pos, wgt, xcur);
  }
}

// Round 2
// 1194.764 us; speedup vs baseline: 1.9070x; 1.9070x over previous
//
#include <hip/hip_runtime.h>
#include <hip/hip_bf16.h>
#include <cstdint>

// Problem constants (B=2,S=1024,D=1024; L=2,E=8,F=2048; k=2)
#define T_TOKENS 2048
#define DDIM 1024
#define FDIM 2048
#define NEXP 8
#define NLAYER 2
#define BM 128
#define RMAX 5120  // 2048*2 + 8*(BM-1) = 5112, rounded up

typedef unsigned short u16;
typedef short bf16x8 __attribute__((ext_vector_type(8)));   // 8 bf16 (4 VGPRs)
typedef u16 u16x8 __attribute__((ext_vector_type(8)));
typedef u16 u16x4v __attribute__((ext_vector_type(4)));
typedef float f32x4 __attribute__((ext_vector_type(4)));

__device__ __forceinline__ u16 bf16_rn(float f) {
  unsigned u = __builtin_bit_cast(unsigned, f);
  u += 0x7fffu + ((u >> 16) & 1u);
  return (u16)(u >> 16);
}
__device__ __forceinline__ float bf16_f(u16 h) {
  unsigned u = ((unsigned)h) << 16;
  return __builtin_bit_cast(float, u);
}

// ---------------- routing: scores = |x . proto_e|, top-2, softmax (f32) ----------------
__global__ __launch_bounds__(256) void route_kernel(
    const float* __restrict__ x, const float* __restrict__ protos,
    int* __restrict__ eid, float* __restrict__ wgt) {
  const int t = blockIdx.x;
  const int tid = threadIdx.x;
  const float* xr = x + (size_t)t * DDIM;
  __shared__ float red[NEXP][256];
  float acc[NEXP];
#pragma unroll
  for (int e = 0; e < NEXP; ++e) acc[e] = 0.f;
  for (int d = tid; d < DDIM; d += 256) {
    float xv = xr[d];
#pragma unroll
    for (int e = 0; e < NEXP; ++e) acc[e] += xv * protos[e * DDIM + d];
  }
#pragma unroll
  for (int e = 0; e < NEXP; ++e) red[e][tid] = acc[e];
  __syncthreads();
  for (int s = 128; s > 0; s >>= 1) {
    if (tid < s) {
#pragma unroll
      for (int e = 0; e < NEXP; ++e) red[e][tid] += red[e][tid + s];
    }
    __syncthreads();
  }
  if (tid == 0) {
    float m1 = -1.f, m2 = -1.f;
    int i1 = 0, i2 = 0;
#pragma unroll
    for (int e = 0; e < NEXP; ++e) {
      float s = fabsf(red[e][0]);
      if (s > m1) { m2 = m1; i2 = i1; m1 = s; i1 = e; }
      else if (s > m2) { m2 = s; i2 = e; }
    }
    float e2 = __expf(m2 - m1);
    float z = 1.f + e2;
    eid[t * 2] = i1;
    eid[t * 2 + 1] = i2;
    wgt[t * 2] = 1.f / z;
    wgt[t * 2 + 1] = e2 / z;
  }
}

// ------------- compaction: ordered per-expert token lists, padded to BM -------------
__global__ void compact_kernel(const int* __restrict__ eid, int* __restrict__ cnt,
                               int* __restrict__ offp, int* __restrict__ row2token,
                               int* __restrict__ pos) {
  const int e = threadIdx.x;
  __shared__ int s_cnt[NEXP], s_off[NEXP];
  if (e < NEXP) {
    int c = 0;
    for (int t = 0; t < T_TOKENS * 2; ++t)
      if (eid[t] == e) c++;
    s_cnt[e] = c;
  }
  __syncthreads();
  if (e == 0) {
    int o = 0;
    for (int i = 0; i < NEXP; ++i) {
      s_off[i] = o;
      o += (s_cnt[i] + BM - 1) & ~(BM - 1);
    }
    for (int r = o; r < RMAX; ++r) row2token[r] = -1;
  }
  __syncthreads();
  if (e < NEXP) {
    int cur = s_off[e];
    for (int t = 0; t < T_TOKENS * 2; ++t) {
      if (eid[t] == e) {
        row2token[cur] = t >> 1;
        pos[t] = cur;
        cur++;
      }
    }
    const int end = s_off[e] + ((s_cnt[e] + BM - 1) & ~(BM - 1));
    for (; cur < end; ++cur) row2token[cur] = -1;
    cnt[e] = s_cnt[e];
    offp[e] = s_off[e];
  }
}

// ------------- gather x rows -> bf16 hi/lo padded row buffers -------------
__global__ __launch_bounds__(256) void gather_kernel(
    const float* __restrict__ x, const int* __restrict__ row2token,
    u16* __restrict__ Ahi, u16* __restrict__ Alo) {
  const int r = blockIdx.x;
  const int t = row2token[r];
  const int c = threadIdx.x * 4;
  float4 v = make_float4(0.f, 0.f, 0.f, 0.f);
  if (t >= 0) v = *(const float4*)(x + (size_t)t * DDIM + c);
  float vv[4] = {v.x, v.y, v.z, v.w};
  u16x4v hi, lo;
#pragma unroll
  for (int i = 0; i < 4; ++i) {
    u16 h = bf16_rn(vv[i]);
    hi[i] = h;
    lo[i] = bf16_rn(vv[i] - bf16_f(h));
  }
  *(u16x4v*)(Ahi + (size_t)r * DDIM + c) = hi;
  *(u16x4v*)(Alo + (size_t)r * DDIM + c) = lo;
}

// ------------- grouped MFMA GEMM -------------
// A (bf16 hi/lo): [RMAX][K]; B (f32): Bbase + e*K*N, [K][N] row-major.
// 128x128 tile, BK=32, 256 thr = 4 waves of 64x64, mfma_f32_16x16x32_bf16.
// SPLIT: C = Ahi*Bhi + Ahi*Blo + Alo*Bhi (f32-grade); else C = Ahi*Bhi.
template <bool RELU, bool SPLIT, bool OUTBF16>
__global__ __launch_bounds__(256, 2) void gemm_mfma(
    const u16* __restrict__ Ahi, const u16* __restrict__ Alo,
    const float* __restrict__ Bbase,
    u16* __restrict__ OutHi, u16* __restrict__ OutLo, float* __restrict__ OutF,
    const int* __restrict__ cnt, const int* __restrict__ offp, int K, int N) {
  const int e = blockIdx.z;
  const int cp = (cnt[e] + BM - 1) & ~(BM - 1);
  if ((int)(blockIdx.y * BM) >= cp) return;
  const int row0 = offp[e] + blockIdx.y * BM;
  const int n0 = blockIdx.x * 128;
  const float* Bp = Bbase + (size_t)e * K * N;

  constexpr int LDP = 40;  // elements per LDS row (80B: conflict-free b128 at 16-lane stride)
  __shared__ u16 lds[(SPLIT ? 4 : 2) * 128 * LDP];
  u16* AsH = lds;
  u16* AsL = lds + (SPLIT ? 128 * LDP : 0);
  u16* BsH = lds + (SPLIT ? 2 : 1) * 128 * LDP;
  u16* BsL = lds + (SPLIT ? 3 : 1) * 128 * LDP;

  const int tid = threadIdx.x;
  const int lane = tid & 63;
  const int wid = tid >> 6;
  const int wr = wid >> 1, wc = wid & 1;     // 2x2 wave grid, 64x64 each
  const int lr = lane & 15, kg = lane >> 4;  // frag row/col and k-group

  f32x4 acc[4][4];
#pragma unroll
  for (int i = 0; i < 4; ++i)
#pragma unroll
    for (int j = 0; j < 4; ++j)
#pragma unroll
      for (int r = 0; r < 4; ++r) acc[i][j][r] = 0.f;

  // staging coords
  const int sar = tid >> 1;          // A row 0..127
  const int sak = (tid & 1) * 16;    // A k 0/16
  const int sbc = tid & 127;         // B col 0..127
  const int sbk = (tid >> 7) * 16;   // B k 0/16

  for (int k0 = 0; k0 < K; k0 += 32) {
    // ---- issue global loads (overlap with previous compute draining) ----
    const u16* ga = Ahi + (size_t)(row0 + sar) * K + k0 + sak;
    int4 va0 = *(const int4*)ga;
    int4 va1 = *(const int4*)(ga + 8);
    int4 vl0, vl1;
    if constexpr (SPLIT) {
      const u16* gl = Alo + (size_t)(row0 + sar) * K + k0 + sak;
      vl0 = *(const int4*)gl;
      vl1 = *(const int4*)(gl + 8);
    }
    float fv[16];
    const float* gb = Bp + (size_t)(k0 + sbk) * N + n0 + sbc;
#pragma unroll
    for (int i = 0; i < 16; ++i) fv[i] = gb[(size_t)i * N];

    __syncthreads();  // previous compute done reading LDS

    // ---- write A tiles ----
    *(int4*)&AsH[sar * LDP + sak] = va0;
    *(int4*)&AsH[sar * LDP + sak + 8] = va1;
    if constexpr (SPLIT) {
      *(int4*)&AsL[sar * LDP + sak] = vl0;
      *(int4*)&AsL[sar * LDP + sak + 8] = vl1;
    }
    // ---- convert + write B tiles (transposed: Bs[col][k]) ----
    u16x8 ph0, ph1, pl0, pl1;
#pragma unroll
    for (int i = 0; i < 8; ++i) {
      u16 h = bf16_rn(fv[i]);
      ph0[i] = h;
      if constexpr (SPLIT) pl0[i] = bf16_rn(fv[i] - bf16_f(h));
    }
#pragma unroll
    for (int i = 0; i < 8; ++i) {
      u16 h = bf16_rn(fv[8 + i]);
      ph1[i] = h;
      if constexpr (SPLIT) pl1[i] = bf16_rn(fv[8 + i] - bf16_f(h));
    }
    *(u16x8*)&BsH[sbc * LDP + sbk] = ph0;
    *(u16x8*)&BsH[sbc * LDP + sbk + 8] = ph1;
    if constexpr (SPLIT) {
      *(u16x8*)&BsL[sbc * LDP + sbk] = pl0;
      *(u16x8*)&BsL[sbc * LDP + sbk + 8] = pl1;
    }
    __syncthreads();

    // ---- fragment loads + MFMA ----
    bf16x8 ah[4], bh[4];
#pragma unroll
    for (int i = 0; i < 4; ++i)
      ah[i] = *(const bf16x8*)&AsH[(wr * 64 + i * 16 + lr) * LDP + kg * 8];
#pragma unroll
    for (int j = 0; j < 4; ++j)
      bh[j] = *(const bf16x8*)&BsH[(wc * 64 + j * 16 + lr) * LDP + kg * 8];
#pragma unroll
    for (int i = 0; i < 4; ++i)
#pragma unroll
      for (int j = 0; j < 4; ++j)
        acc[i][j] = __builtin_amdgcn_mfma_f32_16x16x32_bf16(ah[i], bh[j], acc[i][j], 0, 0, 0);
    if constexpr (SPLIT) {
      bf16x8 al[4], bl[4];
#pragma unroll
      for (int i = 0; i < 4; ++i)
        al[i] = *(const bf16x8*)&AsL[(wr * 64 + i * 16 + lr) * LDP + kg * 8];
#pragma unroll
      for (int j = 0; j < 4; ++j)
        bl[j] = *(const bf16x8*)&BsL[(wc * 64 + j * 16 + lr) * LDP + kg * 8];
#pragma unroll
      for (int i = 0; i < 4; ++i)
#pragma unroll
        for (int j = 0; j < 4; ++j) {
          acc[i][j] = __builtin_amdgcn_mfma_f32_16x16x32_bf16(ah[i], bl[j], acc[i][j], 0, 0, 0);
          acc[i][j] = __builtin_amdgcn_mfma_f32_16x16x32_bf16(al[i], bh[j], acc[i][j], 0, 0, 0);
        }
    }
  }

  // ---- epilogue: D[row=(lane>>4)*4+r][col=lane&15] per 16x16 frag ----
#pragma unroll
  for (int i = 0; i < 4; ++i) {
    const int rg0 = row0 + wr * 64 + i * 16 + kg * 4;
#pragma unroll
    for (int j = 0; j < 4; ++j) {
      const int cg = n0 + wc * 64 + j * 16 + lr;
      f32x4 v = acc[i][j];
#pragma unroll
      for (int r = 0; r < 4; ++r) {
        float f = v[r];
        if (RELU) f = fmaxf(f, 0.f);
        if constexpr (OUTBF16) {
          u16 h = bf16_rn(f);
          OutHi[(size_t)(rg0 + r) * N + cg] = h;
          OutLo[(size_t)(rg0 + r) * N + cg] = bf16_rn(f - bf16_f(h));
        } else {
          OutF[(size_t)(rg0 + r) * N + cg] = f;
        }
      }
    }
  }
}

// ------------- apply: x[t] += w0*y[pos0] + w1*y[pos1] -------------
__global__ __launch_bounds__(256) void apply_kernel(
    const float* __restrict__ ytmp, const int* __restrict__ pos,
    const float* __restrict__ wgt, float* __restrict__ x) {
  const int t = blockIdx.x;
  const int c = threadIdx.x * 4;
  const int p0 = pos[t * 2], p1 = pos[t * 2 + 1];
  const float w0 = wgt[t * 2], w1 = wgt[t * 2 + 1];
  float4 xa = *(float4*)(x + (size_t)t * DDIM + c);
  const float4 y0 = *(const float4*)(ytmp + (size_t)p0 * DDIM + c);
  const float4 y1 = *(const float4*)(ytmp + (size_t)p1 * DDIM + c);
  xa.x += w0 * y0.x + w1 * y1.x;
  xa.y += w0 * y0.y + w1 * y1.y;
  xa.z += w0 * y0.z + w1 * y1.z;
  xa.w += w0 * y0.w + w1 * y1.w;
  *(float4*)(x + (size_t)t * DDIM + c) = xa;
}

extern "C" void kernel_launch(void* const* d_in, const int* in_sizes, int n_in,
                              void* d_out, int out_size, void* d_ws, size_t ws_size,
                              hipStream_t stream) {
  const float* x = (const float*)d_in[0];
  const float* protos = (const float*)d_in[1];
  const float* W1 = (const float*)d_in[2];
  const float* W2 = (const float*)d_in[3];
  float* xcur = (float*)d_out;

  // ws: Ag_hi/lo bf16 [RMAX][D], h_hi/lo bf16 [RMAX][F], ytmp f32 [RMAX][D], meta
  u16* Ag_hi = (u16*)d_ws;
  u16* Ag_lo = Ag_hi + (size_t)RMAX * DDIM;
  u16* h_hi = Ag_lo + (size_t)RMAX * DDIM;
  u16* h_lo = h_hi + (size_t)RMAX * FDIM;
  float* ytmp = (float*)(h_lo + (size_t)RMAX * FDIM);
  float* wgt = ytmp + (size_t)RMAX * DDIM;
  int* eid = (int*)(wgt + T_TOKENS * 2);
  int* pos = eid + T_TOKENS * 2;
  int* cnt = pos + T_TOKENS * 2;
  int* offp = cnt + NEXP;
  int* row2token = offp + NEXP;

  hipMemcpyAsync(xcur, x, (size_t)T_TOKENS * DDIM * sizeof(float),
                 hipMemcpyDeviceToDevice, stream);

  for (int l = 0; l < NLAYER; ++l) {
    route_kernel<<<T_TOKENS, 256, 0, stream>>>(
        xcur, protos + (size_t)l * NEXP * DDIM, eid, wgt);
    compact_kernel<<<1, 64, 0, stream>>>(eid, cnt, offp, row2token, pos);
    gather_kernel<<<RMAX, 256, 0, stream>>>(xcur, row2token, Ag_hi, Ag_lo);
    const float* W1l = W1 + (size_t)l * NEXP * DDIM * FDIM;
    const float* W2l = W2 + (size_t)l * NEXP * FDIM * DDIM;
    if (l == 0) {
      // layer-1 output feeds layer-2 routing: split-bf16 (f32-grade) GEMMs
      gemm_mfma<true, true, true><<<dim3(FDIM / 128, 16, NEXP), 256, 0, stream>>>(
          Ag_hi, Ag_lo, W1l, h_hi, h_lo, nullptr, cnt, offp, DDIM, FDIM);
      gemm_mfma<false, true, false><<<dim3(DDIM / 128, 16, NEXP), 256, 0, stream>>>(
          h_hi, h_lo, W2l, nullptr, nullptr, ytmp, cnt, offp, FDIM, DDIM);
    } else {
      // layer-2 output only feeds the final check (thr 0.112): plain bf16
      gemm_mfma<true, false, true><<<dim3(FDIM / 128, 16, NEXP), 256, 0, stream>>>(
          Ag_hi, Ag_lo, W1l, h_hi, h_lo, nullptr, cnt, offp, DDIM, FDIM);
      gemm_mfma<false, false, false><<<dim3(DDIM / 128, 16, NEXP), 256, 0, stream>>>(
          h_hi, h_lo, W2l, nullptr, nullptr, ytmp, cnt, offp, FDIM, DDIM);
    }
    apply_kernel<<<T_TOKENS, 256, 0, stream>>>(ytmp, pos, wgt, xcur);
  }
}

// Round 3
// 554.076 us; speedup vs baseline: 4.1120x; 2.1563x over previous
//
#include <hip/hip_runtime.h>
#include <hip/hip_bf16.h>
#include <cstdint>

// Problem constants (B=2,S=1024,D=1024; L=2,E=8,F=2048; k=2)
#define T_TOKENS 2048
#define DDIM 1024
#define FDIM 2048
#define NEXP 8
#define NLAYER 2
#define BM 128
#define RMAX 5120  // 2048*2 + 8*(BM-1) = 5112, rounded up

typedef unsigned short u16;
typedef short bf16x8 __attribute__((ext_vector_type(8)));   // 8 bf16 (4 VGPRs)
typedef u16 u16x8 __attribute__((ext_vector_type(8)));
typedef u16 u16x4v __attribute__((ext_vector_type(4)));
typedef float f32x4 __attribute__((ext_vector_type(4)));

__device__ __forceinline__ u16 bf16_rn(float f) {
  unsigned u = __builtin_bit_cast(unsigned, f);
  u += 0x7fffu + ((u >> 16) & 1u);
  return (u16)(u >> 16);
}
__device__ __forceinline__ float bf16_f(u16 h) {
  unsigned u = ((unsigned)h) << 16;
  return __builtin_bit_cast(float, u);
}

// ---------------- routing: scores = |x . proto_e|, top-2, softmax (f32) ----------------
__global__ __launch_bounds__(256) void route_kernel(
    const float* __restrict__ x, const float* __restrict__ protos,
    int* __restrict__ eid, float* __restrict__ wgt) {
  const int t = blockIdx.x;
  const int tid = threadIdx.x;
  const float* xr = x + (size_t)t * DDIM;
  __shared__ float red[NEXP][256];
  float acc[NEXP];
#pragma unroll
  for (int e = 0; e < NEXP; ++e) acc[e] = 0.f;
  for (int d = tid; d < DDIM; d += 256) {
    float xv = xr[d];
#pragma unroll
    for (int e = 0; e < NEXP; ++e) acc[e] += xv * protos[e * DDIM + d];
  }
#pragma unroll
  for (int e = 0; e < NEXP; ++e) red[e][tid] = acc[e];
  __syncthreads();
  for (int s = 128; s > 0; s >>= 1) {
    if (tid < s) {
#pragma unroll
      for (int e = 0; e < NEXP; ++e) red[e][tid] += red[e][tid + s];
    }
    __syncthreads();
  }
  if (tid == 0) {
    float m1 = -1.f, m2 = -1.f;
    int i1 = 0, i2 = 0;
#pragma unroll
    for (int e = 0; e < NEXP; ++e) {
      float s = fabsf(red[e][0]);
      if (s > m1) { m2 = m1; i2 = i1; m1 = s; i1 = e; }
      else if (s > m2) { m2 = s; i2 = e; }
    }
    float e2 = __expf(m2 - m1);
    float z = 1.f + e2;
    eid[t * 2] = i1;
    eid[t * 2 + 1] = i2;
    wgt[t * 2] = 1.f / z;
    wgt[t * 2 + 1] = e2 / z;
  }
}

// ------------- compaction: parallel, deterministic, ordered, padded to BM -------------
// 1 block x 256 threads; each thread owns 16 consecutive (token,slot) entries.
__global__ __launch_bounds__(256) void compact_kernel(
    const int* __restrict__ eid, int* __restrict__ cnt, int* __restrict__ offp,
    int* __restrict__ row2token, int* __restrict__ pos) {
  __shared__ int lcnt[NEXP][256];  // per-thread per-expert counts -> exclusive scan
  __shared__ int s_off[NEXP], s_tot[NEXP];
  const int tid = threadIdx.x;
  const int base = tid * 16;

  int my[16];
#pragma unroll
  for (int i = 0; i < 4; ++i)
    *(int4*)&my[i * 4] = *(const int4*)(eid + base + i * 4);

  // local per-expert counts (unrolled compare-add: no runtime-indexed reg array)
#pragma unroll
  for (int e = 0; e < NEXP; ++e) {
    int c = 0;
#pragma unroll
    for (int i = 0; i < 16; ++i) c += (my[i] == e) ? 1 : 0;
    lcnt[e][tid] = c;
  }

  // parallel init of row2token to -1 (padding/tail default)
  for (int r = tid; r < RMAX; r += 256) row2token[r] = -1;
  __syncthreads();

  // exclusive scan over the 256 threads, one expert per thread (8 active)
  if (tid < NEXP) {
    int run = 0;
    for (int i = 0; i < 256; ++i) {
      int v = lcnt[tid][i];
      lcnt[tid][i] = run;
      run += v;
    }
    s_tot[tid] = run;
  }
  __syncthreads();
  if (tid == 0) {
    int o = 0;
    for (int e = 0; e < NEXP; ++e) {
      s_off[e] = o;
      o += (s_tot[e] + BM - 1) & ~(BM - 1);
    }
  }
  __syncthreads();

  // scatter: rank = s_off[e] + scan[e][tid] + (local occurrences before i)
  int myoff[NEXP];
#pragma unroll
  for (int e = 0; e < NEXP; ++e) myoff[e] = s_off[e] + lcnt[e][tid];
#pragma unroll
  for (int i = 0; i < 16; ++i) {
    int r = 0;
#pragma unroll
    for (int e = 0; e < NEXP; ++e) r = (my[i] == e) ? myoff[e] : r;
    row2token[r] = (base + i) >> 1;
    pos[base + i] = r;
#pragma unroll
    for (int e = 0; e < NEXP; ++e) myoff[e] += (my[i] == e) ? 1 : 0;
  }

  if (tid < NEXP) {
    cnt[tid] = s_tot[tid];
    offp[tid] = s_off[tid];
  }
}

// ------------- gather x rows -> bf16 hi/lo padded row buffers -------------
__global__ __launch_bounds__(256) void gather_kernel(
    const float* __restrict__ x, const int* __restrict__ row2token,
    u16* __restrict__ Ahi, u16* __restrict__ Alo) {
  const int r = blockIdx.x;
  const int t = row2token[r];
  const int c = threadIdx.x * 4;
  float4 v = make_float4(0.f, 0.f, 0.f, 0.f);
  if (t >= 0) v = *(const float4*)(x + (size_t)t * DDIM + c);
  float vv[4] = {v.x, v.y, v.z, v.w};
  u16x4v hi, lo;
#pragma unroll
  for (int i = 0; i < 4; ++i) {
    u16 h = bf16_rn(vv[i]);
    hi[i] = h;
    lo[i] = bf16_rn(vv[i] - bf16_f(h));
  }
  *(u16x4v*)(Ahi + (size_t)r * DDIM + c) = hi;
  *(u16x4v*)(Alo + (size_t)r * DDIM + c) = lo;
}

// ------------- grouped MFMA GEMM -------------
// A (bf16 hi/lo): [RMAX][K]; B (f32): Bbase + e*K*N, [K][N] row-major.
// 128x128 tile, BK=32, 256 thr = 4 waves of 64x64, mfma_f32_16x16x32_bf16.
// SPLIT: C = Ahi*Bhi + Ahi*Blo + Alo*Bhi (f32-grade); else C = Ahi*Bhi.
template <bool RELU, bool SPLIT, bool OUTBF16>
__global__ __launch_bounds__(256, 2) void gemm_mfma(
    const u16* __restrict__ Ahi, const u16* __restrict__ Alo,
    const float* __restrict__ Bbase,
    u16* __restrict__ OutHi, u16* __restrict__ OutLo, float* __restrict__ OutF,
    const int* __restrict__ cnt, const int* __restrict__ offp, int K, int N) {
  const int e = blockIdx.z;
  const int cp = (cnt[e] + BM - 1) & ~(BM - 1);
  if ((int)(blockIdx.y * BM) >= cp) return;
  const int row0 = offp[e] + blockIdx.y * BM;
  const int n0 = blockIdx.x * 128;
  const float* Bp = Bbase + (size_t)e * K * N;

  constexpr int LDP = 40;  // elements per LDS row (80B: conflict-free b128 at 16-lane stride)
  __shared__ u16 lds[(SPLIT ? 4 : 2) * 128 * LDP];
  u16* AsH = lds;
  u16* AsL = lds + (SPLIT ? 128 * LDP : 0);
  u16* BsH = lds + (SPLIT ? 2 : 1) * 128 * LDP;
  u16* BsL = lds + (SPLIT ? 3 : 1) * 128 * LDP;

  const int tid = threadIdx.x;
  const int lane = tid & 63;
  const int wid = tid >> 6;
  const int wr = wid >> 1, wc = wid & 1;     // 2x2 wave grid, 64x64 each
  const int lr = lane & 15, kg = lane >> 4;  // frag row/col and k-group

  f32x4 acc[4][4];
#pragma unroll
  for (int i = 0; i < 4; ++i)
#pragma unroll
    for (int j = 0; j < 4; ++j)
#pragma unroll
      for (int r = 0; r < 4; ++r) acc[i][j][r] = 0.f;

  // staging coords
  const int sar = tid >> 1;          // A row 0..127
  const int sak = (tid & 1) * 16;    // A k 0/16
  const int sbc = tid & 127;         // B col 0..127
  const int sbk = (tid >> 7) * 16;   // B k 0/16

  for (int k0 = 0; k0 < K; k0 += 32) {
    // ---- issue global loads (overlap with previous compute draining) ----
    const u16* ga = Ahi + (size_t)(row0 + sar) * K + k0 + sak;
    int4 va0 = *(const int4*)ga;
    int4 va1 = *(const int4*)(ga + 8);
    int4 vl0, vl1;
    if constexpr (SPLIT) {
      const u16* gl = Alo + (size_t)(row0 + sar) * K + k0 + sak;
      vl0 = *(const int4*)gl;
      vl1 = *(const int4*)(gl + 8);
    }
    float fv[16];
    const float* gb = Bp + (size_t)(k0 + sbk) * N + n0 + sbc;
#pragma unroll
    for (int i = 0; i < 16; ++i) fv[i] = gb[(size_t)i * N];

    __syncthreads();  // previous compute done reading LDS

    // ---- write A tiles ----
    *(int4*)&AsH[sar * LDP + sak] = va0;
    *(int4*)&AsH[sar * LDP + sak + 8] = va1;
    if constexpr (SPLIT) {
      *(int4*)&AsL[sar * LDP + sak] = vl0;
      *(int4*)&AsL[sar * LDP + sak + 8] = vl1;
    }
    // ---- convert + write B tiles (transposed: Bs[col][k]) ----
    u16x8 ph0, ph1, pl0, pl1;
#pragma unroll
    for (int i = 0; i < 8; ++i) {
      u16 h = bf16_rn(fv[i]);
      ph0[i] = h;
      if constexpr (SPLIT) pl0[i] = bf16_rn(fv[i] - bf16_f(h));
    }
#pragma unroll
    for (int i = 0; i < 8; ++i) {
      u16 h = bf16_rn(fv[8 + i]);
      ph1[i] = h;
      if constexpr (SPLIT) pl1[i] = bf16_rn(fv[8 + i] - bf16_f(h));
    }
    *(u16x8*)&BsH[sbc * LDP + sbk] = ph0;
    *(u16x8*)&BsH[sbc * LDP + sbk + 8] = ph1;
    if constexpr (SPLIT) {
      *(u16x8*)&BsL[sbc * LDP + sbk] = pl0;
      *(u16x8*)&BsL[sbc * LDP + sbk + 8] = pl1;
    }
    __syncthreads();

    // ---- fragment loads + MFMA ----
    bf16x8 ah[4], bh[4];
#pragma unroll
    for (int i = 0; i < 4; ++i)
      ah[i] = *(const bf16x8*)&AsH[(wr * 64 + i * 16 + lr) * LDP + kg * 8];
#pragma unroll
    for (int j = 0; j < 4; ++j)
      bh[j] = *(const bf16x8*)&BsH[(wc * 64 + j * 16 + lr) * LDP + kg * 8];
#pragma unroll
    for (int i = 0; i < 4; ++i)
#pragma unroll
      for (int j = 0; j < 4; ++j)
        acc[i][j] = __builtin_amdgcn_mfma_f32_16x16x32_bf16(ah[i], bh[j], acc[i][j], 0, 0, 0);
    if constexpr (SPLIT) {
      bf16x8 al[4], bl[4];
#pragma unroll
      for (int i = 0; i < 4; ++i)
        al[i] = *(const bf16x8*)&AsL[(wr * 64 + i * 16 + lr) * LDP + kg * 8];
#pragma unroll
      for (int j = 0; j < 4; ++j)
        bl[j] = *(const bf16x8*)&BsL[(wc * 64 + j * 16 + lr) * LDP + kg * 8];
#pragma unroll
      for (int i = 0; i < 4; ++i)
#pragma unroll
        for (int j = 0; j < 4; ++j) {
          acc[i][j] = __builtin_amdgcn_mfma_f32_16x16x32_bf16(ah[i], bl[j], acc[i][j], 0, 0, 0);
          acc[i][j] = __builtin_amdgcn_mfma_f32_16x16x32_bf16(al[i], bh[j], acc[i][j], 0, 0, 0);
        }
    }
  }

  // ---- epilogue: D[row=(lane>>4)*4+r][col=lane&15] per 16x16 frag ----
#pragma unroll
  for (int i = 0; i < 4; ++i) {
    const int rg0 = row0 + wr * 64 + i * 16 + kg * 4;
#pragma unroll
    for (int j = 0; j < 4; ++j) {
      const int cg = n0 + wc * 64 + j * 16 + lr;
      f32x4 v = acc[i][j];
#pragma unroll
      for (int r = 0; r < 4; ++r) {
        float f = v[r];
        if (RELU) f = fmaxf(f, 0.f);
        if constexpr (OUTBF16) {
          u16 h = bf16_rn(f);
          OutHi[(size_t)(rg0 + r) * N + cg] = h;
          OutLo[(size_t)(rg0 + r) * N + cg] = bf16_rn(f - bf16_f(h));
        } else {
          OutF[(size_t)(rg0 + r) * N + cg] = f;
        }
      }
    }
  }
}

// ------------- apply: x[t] += w0*y[pos0] + w1*y[pos1] -------------
__global__ __launch_bounds__(256) void apply_kernel(
    const float* __restrict__ ytmp, const int* __restrict__ pos,
    const float* __restrict__ wgt, float* __restrict__ x) {
  const int t = blockIdx.x;
  const int c = threadIdx.x * 4;
  const int p0 = pos[t * 2], p1 = pos[t * 2 + 1];
  const float w0 = wgt[t * 2], w1 = wgt[t * 2 + 1];
  float4 xa = *(float4*)(x + (size_t)t * DDIM + c);
  const float4 y0 = *(const float4*)(ytmp + (size_t)p0 * DDIM + c);
  const float4 y1 = *(const float4*)(ytmp + (size_t)p1 * DDIM + c);
  xa.x += w0 * y0.x + w1 * y1.x;
  xa.y += w0 * y0.y + w1 * y1.y;
  xa.z += w0 * y0.z + w1 * y1.z;
  xa.w += w0 * y0.w + w1 * y1.w;
  *(float4*)(x + (size_t)t * DDIM + c) = xa;
}

extern "C" void kernel_launch(void* const* d_in, const int* in_sizes, int n_in,
                              void* d_out, int out_size, void* d_ws, size_t ws_size,
                              hipStream_t stream) {
  const float* x = (const float*)d_in[0];
  const float* protos = (const float*)d_in[1];
  const float* W1 = (const float*)d_in[2];
  const float* W2 = (const float*)d_in[3];
  float* xcur = (float*)d_out;

  // ws: Ag_hi/lo bf16 [RMAX][D], h_hi/lo bf16 [RMAX][F], ytmp f32 [RMAX][D], meta
  u16* Ag_hi = (u16*)d_ws;
  u16* Ag_lo = Ag_hi + (size_t)RMAX * DDIM;
  u16* h_hi = Ag_lo + (size_t)RMAX * DDIM;
  u16* h_lo = h_hi + (size_t)RMAX * FDIM;
  float* ytmp = (float*)(h_lo + (size_t)RMAX * FDIM);
  float* wgt = ytmp + (size_t)RMAX * DDIM;
  int* eid = (int*)(wgt + T_TOKENS * 2);
  int* pos = eid + T_TOKENS * 2;
  int* cnt = pos + T_TOKENS * 2;
  int* offp = cnt + NEXP;
  int* row2token = offp + NEXP;

  hipMemcpyAsync(xcur, x, (size_t)T_TOKENS * DDIM * sizeof(float),
                 hipMemcpyDeviceToDevice, stream);

  for (int l = 0; l < NLAYER; ++l) {
    route_kernel<<<T_TOKENS, 256, 0, stream>>>(
        xcur, protos + (size_t)l * NEXP * DDIM, eid, wgt);
    compact_kernel<<<1, 256, 0, stream>>>(eid, cnt, offp, row2token, pos);
    gather_kernel<<<RMAX, 256, 0, stream>>>(xcur, row2token, Ag_hi, Ag_lo);
    const float* W1l = W1 + (size_t)l * NEXP * DDIM * FDIM;
    const float* W2l = W2 + (size_t)l * NEXP * FDIM * DDIM;
    if (l == 0) {
      // layer-1 output feeds layer-2 routing: split-bf16 (f32-grade) GEMMs
      gemm_mfma<true, true, true><<<dim3(FDIM / 128, 32, NEXP), 256, 0, stream>>>(
          Ag_hi, Ag_lo, W1l, h_hi, h_lo, nullptr, cnt, offp, DDIM, FDIM);
      gemm_mfma<false, true, false><<<dim3(DDIM / 128, 32, NEXP), 256, 0, stream>>>(
          h_hi, h_lo, W2l, nullptr, nullptr, ytmp, cnt, offp, FDIM, DDIM);
    } else {
      // layer-2 output only feeds the final check (thr 0.112): plain bf16
      gemm_mfma<true, false, true><<<dim3(FDIM / 128, 32, NEXP), 256, 0, stream>>>(
          Ag_hi, Ag_lo, W1l, h_hi, h_lo, nullptr, cnt, offp, DDIM, FDIM);
      gemm_mfma<false, false, false><<<dim3(DDIM / 128, 32, NEXP), 256, 0, stream>>>(
          h_hi, h_lo, W2l, nullptr, nullptr, ytmp, cnt, offp, FDIM, DDIM);
    }
    apply_kernel<<<T_TOKENS, 256, 0, stream>>>(ytmp, pos, wgt, xcur);
  }
}

// Round 4
// 412.621 us; speedup vs baseline: 5.5217x; 1.3428x over previous
//
#include <hip/hip_runtime.h>
#include <hip/hip_bf16.h>
#include <cstdint>

// Problem constants (B=2,S=1024,D=1024; L=2,E=8,F=2048; k=2)
#define T_TOKENS 2048
#define DDIM 1024
#define FDIM 2048
#define NEXP 8
#define NLAYER 2
#define BM 128
#define RMAX 5120  // 2048*2 + 8*(BM-1) = 5112, rounded up

// Tiled operand layout: 128(rows) x 64(k) bf16 tiles, 8192 elements (16 KB),
// element order: (((sub*4+kg)*128 + row)*8 + (k&7)), sub=(k>>5)&1, kg=(k>>3)&3.
// This is exactly MFMA fragment order: a linear LDS copy of a tile is
// fragment-readable with conflict-free ds_read_b128.
#define TILE_EL 8192

typedef unsigned short u16;
typedef short bf16x8 __attribute__((ext_vector_type(8)));   // 8 bf16 (4 VGPRs)
typedef u16 u16x8 __attribute__((ext_vector_type(8)));
typedef u16 u16x4v __attribute__((ext_vector_type(4)));
typedef float f32x4 __attribute__((ext_vector_type(4)));

__device__ __forceinline__ u16 bf16_rn(float f) {
  unsigned u = __builtin_bit_cast(unsigned, f);
  u += 0x7fffu + ((u >> 16) & 1u);
  return (u16)(u >> 16);
}
__device__ __forceinline__ float bf16_f(u16 h) {
  unsigned u = ((unsigned)h) << 16;
  return __builtin_bit_cast(float, u);
}

// async global->LDS, 16B per lane; lds dest = wave-uniform base + lane*16 (HW)
__device__ __forceinline__ void gl16(const void* g, void* l) {
  __builtin_amdgcn_global_load_lds((const __attribute__((address_space(1))) void*)g,
                                   (__attribute__((address_space(3))) void*)l, 16, 0, 0);
}

// ---------------- routing: scores = |x . proto_e|, top-2, softmax (f32) ----------------
__global__ __launch_bounds__(256) void route_kernel(
    const float* __restrict__ x, const float* __restrict__ protos,
    int* __restrict__ eid, float* __restrict__ wgt) {
  const int t = blockIdx.x;
  const int tid = threadIdx.x;
  const float* xr = x + (size_t)t * DDIM;
  __shared__ float red[NEXP][256];
  float acc[NEXP];
#pragma unroll
  for (int e = 0; e < NEXP; ++e) acc[e] = 0.f;
  for (int d = tid; d < DDIM; d += 256) {
    float xv = xr[d];
#pragma unroll
    for (int e = 0; e < NEXP; ++e) acc[e] += xv * protos[e * DDIM + d];
  }
#pragma unroll
  for (int e = 0; e < NEXP; ++e) red[e][tid] = acc[e];
  __syncthreads();
  for (int s = 128; s > 0; s >>= 1) {
    if (tid < s) {
#pragma unroll
      for (int e = 0; e < NEXP; ++e) red[e][tid] += red[e][tid + s];
    }
    __syncthreads();
  }
  if (tid == 0) {
    float m1 = -1.f, m2 = -1.f;
    int i1 = 0, i2 = 0;
#pragma unroll
    for (int e = 0; e < NEXP; ++e) {
      float s = fabsf(red[e][0]);
      if (s > m1) { m2 = m1; i2 = i1; m1 = s; i1 = e; }
      else if (s > m2) { m2 = s; i2 = e; }
    }
    float e2 = __expf(m2 - m1);
    float z = 1.f + e2;
    eid[t * 2] = i1;
    eid[t * 2 + 1] = i2;
    wgt[t * 2] = 1.f / z;
    wgt[t * 2 + 1] = e2 / z;
  }
}

// ------------- compaction: parallel, deterministic, ordered, padded to BM -------------
__global__ __launch_bounds__(256) void compact_kernel(
    const int* __restrict__ eid, int* __restrict__ cnt, int* __restrict__ offp,
    int* __restrict__ row2token, int* __restrict__ pos) {
  __shared__ int lcnt[NEXP][256];
  __shared__ int s_off[NEXP], s_tot[NEXP];
  const int tid = threadIdx.x;
  const int base = tid * 16;

  int my[16];
#pragma unroll
  for (int i = 0; i < 4; ++i)
    *(int4*)&my[i * 4] = *(const int4*)(eid + base + i * 4);

#pragma unroll
  for (int e = 0; e < NEXP; ++e) {
    int c = 0;
#pragma unroll
    for (int i = 0; i < 16; ++i) c += (my[i] == e) ? 1 : 0;
    lcnt[e][tid] = c;
  }

  for (int r = tid; r < RMAX; r += 256) row2token[r] = -1;
  __syncthreads();

  if (tid < NEXP) {
    int run = 0;
    for (int i = 0; i < 256; ++i) {
      int v = lcnt[tid][i];
      lcnt[tid][i] = run;
      run += v;
    }
    s_tot[tid] = run;
  }
  __syncthreads();
  if (tid == 0) {
    int o = 0;
    for (int e = 0; e < NEXP; ++e) {
      s_off[e] = o;
      o += (s_tot[e] + BM - 1) & ~(BM - 1);
    }
  }
  __syncthreads();

  int myoff[NEXP];
#pragma unroll
  for (int e = 0; e < NEXP; ++e) myoff[e] = s_off[e] + lcnt[e][tid];
#pragma unroll
  for (int i = 0; i < 16; ++i) {
    int r = 0;
#pragma unroll
    for (int e = 0; e < NEXP; ++e) r = (my[i] == e) ? myoff[e] : r;
    row2token[r] = (base + i) >> 1;
    pos[base + i] = r;
#pragma unroll
    for (int e = 0; e < NEXP; ++e) myoff[e] += (my[i] == e) ? 1 : 0;
  }

  if (tid < NEXP) {
    cnt[tid] = s_tot[tid];
    offp[tid] = s_off[tid];
  }
}

// ------------- gather x rows -> bf16 hi/lo TILED buffers -------------
__global__ __launch_bounds__(256) void gather_kernel(
    const float* __restrict__ x, const int* __restrict__ row2token,
    u16* __restrict__ Ahi, u16* __restrict__ Alo) {
  const int r = blockIdx.x;
  const int t = row2token[r];
  const int c = threadIdx.x * 4;  // k-element base (0..1023, step 4)
  float4 v = make_float4(0.f, 0.f, 0.f, 0.f);
  if (t >= 0) v = *(const float4*)(x + (size_t)t * DDIM + c);
  float vv[4] = {v.x, v.y, v.z, v.w};
  u16x4v hi, lo;
#pragma unroll
  for (int i = 0; i < 4; ++i) {
    u16 h = bf16_rn(vv[i]);
    hi[i] = h;
    lo[i] = bf16_rn(vv[i] - bf16_f(h));
  }
  const int ksel = ((c >> 5) & 1) * 4 + ((c >> 3) & 3);
  const size_t el = ((size_t)(r >> 7) * (DDIM >> 6) + (c >> 6)) * TILE_EL +
                    (size_t)(ksel * 128 + (r & 127)) * 8 + (c & 7);
  *(u16x4v*)(Ahi + el) = hi;
  *(u16x4v*)(Alo + el) = lo;
}

// ------------- W convert: f32 [e][K][N] -> bf16 hi(/lo) tiled [e][N/128][K/64] -------------
template <bool LO>
__global__ __launch_bounds__(256) void wconv_kernel(
    const float* __restrict__ W, u16* __restrict__ Hi, u16* __restrict__ Lo,
    int K, int N) {
  const int e = blockIdx.z, nb = blockIdx.x, kb = blockIdx.y;
  const float* Wp = W + ((size_t)e * K + (size_t)kb * 64) * N + nb * 128;
  __shared__ float tile[64][129];
  const int t = threadIdx.x;
  // coalesced read of the 64x128 f32 tile
#pragma unroll
  for (int i = 0; i < 8; ++i) {
    const int f4 = i * 256 + t;        // float4 index in [0,2048)
    const int kr = f4 >> 5;            // row (32 float4 per row)
    const int c4 = (f4 & 31) * 4;      // col
    float4 v = *(const float4*)(Wp + (size_t)kr * N + c4);
    *(float4*)&tile[kr][c4] = v;
  }
  __syncthreads();
  const size_t tb = ((size_t)e * (N >> 7) * (K >> 6) + (size_t)nb * (K >> 6) + kb) * TILE_EL;
#pragma unroll
  for (int j = 0; j < 4; ++j) {
    const int cid = j * 256 + t;       // chunk id 0..1023
    const int n = cid & 127, ksel = cid >> 7;
    const int kbase = (ksel >> 2) * 32 + (ksel & 3) * 8;
    u16x8 hv, lv;
#pragma unroll
    for (int i = 0; i < 8; ++i) {
      float f = tile[kbase + i][n];
      u16 h = bf16_rn(f);
      hv[i] = h;
      if (LO) lv[i] = bf16_rn(f - bf16_f(h));
    }
    *(u16x8*)(Hi + tb + (size_t)cid * 8) = hv;   // fully coalesced
    if (LO) *(u16x8*)(Lo + tb + (size_t)cid * 8) = lv;
  }
}

// ------------- grouped MFMA GEMM, tiled operands, global_load_lds staging -------------
// A tiles: [rowblk][K/64]; B tiles: [e][N/128][K/64]. 128x128 tile, BK=64,
// 4 waves 64x64 each, mfma_f32_16x16x32_bf16.
// SPLIT: C = Ah*Bh + Ah*Bl + Al*Bh; OUTBF16: write hi(/lo per OUTLO) tiled; else f32 row-major.
template <bool RELU, bool SPLIT, bool OUTBF16, bool OUTLO>
__global__ __launch_bounds__(256, SPLIT ? 2 : 4) void gemm_mfma(
    const u16* __restrict__ Ahi, const u16* __restrict__ Alo,
    const u16* __restrict__ Bhi, const u16* __restrict__ Blo,
    u16* __restrict__ OutHi, u16* __restrict__ OutLo, float* __restrict__ OutF,
    const int* __restrict__ cnt, const int* __restrict__ offp, int K, int N) {
  const int e = blockIdx.z;
  const int cp = (cnt[e] + BM - 1) & ~(BM - 1);
  if ((int)(blockIdx.y * BM) >= cp) return;
  const int row0 = offp[e] + blockIdx.y * BM;
  const int n0 = blockIdx.x * 128;
  const int nkb = K >> 6;

  __shared__ u16 lds[(SPLIT ? 4 : 2) * TILE_EL];
  u16* AsH = lds;
  u16* BsH = lds + TILE_EL;
  u16* AsL = SPLIT ? (lds + 2 * TILE_EL) : nullptr;
  u16* BsL = SPLIT ? (lds + 3 * TILE_EL) : nullptr;

  const int tid = threadIdx.x;
  const int lane = tid & 63;
  const int wid = tid >> 6;
  const int wr = wid >> 1, wc = wid & 1;     // 2x2 wave grid, 64x64 each
  const int lr = lane & 15, kg = lane >> 4;

  const int sgb = wid * 1024 + (lane << 4);  // staging byte offset, global side
  const int slb = wid * 1024;                // staging byte offset, LDS side (lane*16 by HW)

  f32x4 acc[4][4];
#pragma unroll
  for (int i = 0; i < 4; ++i)
#pragma unroll
    for (int j = 0; j < 4; ++j)
#pragma unroll
      for (int r = 0; r < 4; ++r) acc[i][j][r] = 0.f;

  const size_t abase = (size_t)(row0 >> 7) * nkb * TILE_EL;
  const size_t bbase = ((size_t)e * (N >> 7) + (n0 >> 7)) * nkb * TILE_EL;

  for (int kb = 0; kb < nkb; ++kb) {
    const char* ga = (const char*)(Ahi + abase + (size_t)kb * TILE_EL);
    const char* gb = (const char*)(Bhi + bbase + (size_t)kb * TILE_EL);
#pragma unroll
    for (int is = 0; is < 4; ++is) {
      gl16(ga + is * 4096 + sgb, (char*)AsH + is * 4096 + slb);
      gl16(gb + is * 4096 + sgb, (char*)BsH + is * 4096 + slb);
    }
    if constexpr (SPLIT) {
      const char* gal = (const char*)(Alo + abase + (size_t)kb * TILE_EL);
      const char* gbl = (const char*)(Blo + bbase + (size_t)kb * TILE_EL);
#pragma unroll
      for (int is = 0; is < 4; ++is) {
        gl16(gal + is * 4096 + sgb, (char*)AsL + is * 4096 + slb);
        gl16(gbl + is * 4096 + sgb, (char*)BsL + is * 4096 + slb);
      }
    }
    __syncthreads();  // drains vmcnt(0): all tiles staged

#pragma unroll
    for (int sub = 0; sub < 2; ++sub) {
      const int fb = (sub * 4 + kg) * 1024;  // element base of this k-chunk region
      bf16x8 ah[4], bh[4];
#pragma unroll
      for (int i = 0; i < 4; ++i)
        ah[i] = *(const bf16x8*)&AsH[fb + (wr * 64 + i * 16 + lr) * 8];
#pragma unroll
      for (int j = 0; j < 4; ++j)
        bh[j] = *(const bf16x8*)&BsH[fb + (wc * 64 + j * 16 + lr) * 8];
#pragma unroll
      for (int i = 0; i < 4; ++i)
#pragma unroll
        for (int j = 0; j < 4; ++j)
          acc[i][j] = __builtin_amdgcn_mfma_f32_16x16x32_bf16(ah[i], bh[j], acc[i][j], 0, 0, 0);
      if constexpr (SPLIT) {
        bf16x8 al[4], bl[4];
#pragma unroll
        for (int i = 0; i < 4; ++i)
          al[i] = *(const bf16x8*)&AsL[fb + (wr * 64 + i * 16 + lr) * 8];
#pragma unroll
        for (int j = 0; j < 4; ++j)
          bl[j] = *(const bf16x8*)&BsL[fb + (wc * 64 + j * 16 + lr) * 8];
#pragma unroll
        for (int i = 0; i < 4; ++i)
#pragma unroll
          for (int j = 0; j < 4; ++j) {
            acc[i][j] = __builtin_amdgcn_mfma_f32_16x16x32_bf16(ah[i], bl[j], acc[i][j], 0, 0, 0);
            acc[i][j] = __builtin_amdgcn_mfma_f32_16x16x32_bf16(al[i], bh[j], acc[i][j], 0, 0, 0);
          }
      }
    }
    __syncthreads();  // all reads done before next stage overwrites
  }

  // ---- epilogue: C/D frag: col = lane&15 (=lr), row = (lane>>4)*4 + r (=kg*4+r) ----
  const int nkbO = N >> 6;  // output viewed as next GEMM's A: k-blocks along N
#pragma unroll
  for (int i = 0; i < 4; ++i) {
#pragma unroll
    for (int j = 0; j < 4; ++j) {
      const int Cj = n0 + wc * 64 + j * 16 + lr;
      f32x4 v = acc[i][j];
#pragma unroll
      for (int r = 0; r < 4; ++r) {
        const int R = row0 + wr * 64 + i * 16 + kg * 4 + r;
        float f = v[r];
        if (RELU) f = fmaxf(f, 0.f);
        if constexpr (OUTBF16) {
          const int ksel = ((Cj >> 5) & 1) * 4 + ((Cj >> 3) & 3);
          const size_t el = ((size_t)(R >> 7) * nkbO + (Cj >> 6)) * TILE_EL +
                            (size_t)(ksel * 128 + (R & 127)) * 8 + (Cj & 7);
          u16 h = bf16_rn(f);
          OutHi[el] = h;
          if (OUTLO) OutLo[el] = bf16_rn(f - bf16_f(h));
        } else {
          OutF[(size_t)R * N + Cj] = f;
        }
      }
    }
  }
}

// ------------- apply: x[t] += w0*y[pos0] + w1*y[pos1] -------------
__global__ __launch_bounds__(256) void apply_kernel(
    const float* __restrict__ ytmp, const int* __restrict__ pos,
    const float* __restrict__ wgt, float* __restrict__ x) {
  const int t = blockIdx.x;
  const int c = threadIdx.x * 4;
  const int p0 = pos[t * 2], p1 = pos[t * 2 + 1];
  const float w0 = wgt[t * 2], w1 = wgt[t * 2 + 1];
  float4 xa = *(float4*)(x + (size_t)t * DDIM + c);
  const float4 y0 = *(const float4*)(ytmp + (size_t)p0 * DDIM + c);
  const float4 y1 = *(const float4*)(ytmp + (size_t)p1 * DDIM + c);
  xa.x += w0 * y0.x + w1 * y1.x;
  xa.y += w0 * y0.y + w1 * y1.y;
  xa.z += w0 * y0.z + w1 * y1.z;
  xa.w += w0 * y0.w + w1 * y1.w;
  *(float4*)(x + (size_t)t * DDIM + c) = xa;
}

extern "C" void kernel_launch(void* const* d_in, const int* in_sizes, int n_in,
                              void* d_out, int out_size, void* d_ws, size_t ws_size,
                              hipStream_t stream) {
  const float* x = (const float*)d_in[0];
  const float* protos = (const float*)d_in[1];
  const float* W1 = (const float*)d_in[2];
  const float* W2 = (const float*)d_in[3];
  float* xcur = (float*)d_out;

  // ws layout (~151 MB):
  //   W_hi, W_lo: 16.8M u16 each (shared, converted before each GEMM)
  //   Ag_hi/lo: 5120*1024 u16; h_hi/lo: 5120*2048 u16; ytmp: 5120*1024 f32; meta
  u16* W_hi = (u16*)d_ws;
  u16* W_lo = W_hi + (size_t)NEXP * DDIM * FDIM;
  u16* Ag_hi = W_lo + (size_t)NEXP * DDIM * FDIM;
  u16* Ag_lo = Ag_hi + (size_t)RMAX * DDIM;
  u16* h_hi = Ag_lo + (size_t)RMAX * DDIM;
  u16* h_lo = h_hi + (size_t)RMAX * FDIM;
  float* ytmp = (float*)(h_lo + (size_t)RMAX * FDIM);
  float* wgt = ytmp + (size_t)RMAX * DDIM;
  int* eid = (int*)(wgt + T_TOKENS * 2);
  int* pos = eid + T_TOKENS * 2;
  int* cnt = pos + T_TOKENS * 2;
  int* offp = cnt + NEXP;
  int* row2token = offp + NEXP;

  hipMemcpyAsync(xcur, x, (size_t)T_TOKENS * DDIM * sizeof(float),
                 hipMemcpyDeviceToDevice, stream);

  for (int l = 0; l < NLAYER; ++l) {
    route_kernel<<<T_TOKENS, 256, 0, stream>>>(
        xcur, protos + (size_t)l * NEXP * DDIM, eid, wgt);
    compact_kernel<<<1, 256, 0, stream>>>(eid, cnt, offp, row2token, pos);
    gather_kernel<<<RMAX, 256, 0, stream>>>(xcur, row2token, Ag_hi, Ag_lo);
    const float* W1l = W1 + (size_t)l * NEXP * DDIM * FDIM;
    const float* W2l = W2 + (size_t)l * NEXP * FDIM * DDIM;
    if (l == 0) {
      // layer-1 output feeds layer-2 routing: split-bf16 (f32-grade) GEMMs
      wconv_kernel<true><<<dim3(FDIM / 128, DDIM / 64, NEXP), 256, 0, stream>>>(
          W1l, W_hi, W_lo, DDIM, FDIM);
      gemm_mfma<true, true, true, true><<<dim3(FDIM / 128, 32, NEXP), 256, 0, stream>>>(
          Ag_hi, Ag_lo, W_hi, W_lo, h_hi, h_lo, nullptr, cnt, offp, DDIM, FDIM);
      wconv_kernel<true><<<dim3(DDIM / 128, FDIM / 64, NEXP), 256, 0, stream>>>(
          W2l, W_hi, W_lo, FDIM, DDIM);
      gemm_mfma<false, true, false, false><<<dim3(DDIM / 128, 32, NEXP), 256, 0, stream>>>(
          h_hi, h_lo, W_hi, W_lo, nullptr, nullptr, ytmp, cnt, offp, FDIM, DDIM);
    } else {
      // layer-2 output only feeds the final check (thr 0.112): plain bf16
      wconv_kernel<false><<<dim3(FDIM / 128, DDIM / 64, NEXP), 256, 0, stream>>>(
          W1l, W_hi, nullptr, DDIM, FDIM);
      gemm_mfma<true, false, true, false><<<dim3(FDIM / 128, 32, NEXP), 256, 0, stream>>>(
          Ag_hi, nullptr, W_hi, nullptr, h_hi, nullptr, nullptr, cnt, offp, DDIM, FDIM);
      wconv_kernel<false><<<dim3(DDIM / 128, FDIM / 64, NEXP), 256, 0, stream>>>(
          W2l, W_hi, nullptr, FDIM, DDIM);
      gemm_mfma<false, false, false, false><<<dim3(DDIM / 128, 32, NEXP), 256, 0, stream>>>(
          h_hi, nullptr, W_hi, nullptr, nullptr, nullptr, ytmp, cnt, offp, FDIM, DDIM);
    }
    apply_kernel<<<T_TOKENS, 256, 0, stream>>>(ytmp, pos, wgt, xcur);
  }
}